// Round 6
// baseline (225.887 us; speedup 1.0000x reference)
//
#include <hip/hip_runtime.h>
#include <cmath>

#define D 128
#define BM 128   // A rows per block tile (held in registers)
#define BN 64    // B cols per staged half-tile (LDS)
#define NSEG 12  // segments per strip-pair -> 64*12 = 768 blocks = 3/CU exactly
#define LOG2E 1.4426950408889634

typedef __attribute__((ext_vector_type(8))) _Float16 f16x8;
typedef __attribute__((ext_vector_type(4))) float f32x4;
typedef __attribute__((ext_vector_type(2))) float f32x2;

// async global->LDS 16B copy (global_load_lds_dwordx4); LDS dst is
// wave-uniform base + lane*16 -- swizzle lives in gsrc.
// R9/R10: ALWAYS pass 0 for the builtin immediate; fold offsets into ptr.
__device__ __forceinline__ void async_cp16(const void* g, void* l) {
    __builtin_amdgcn_global_load_lds(
        (__attribute__((address_space(1))) void*)g,
        (__attribute__((address_space(3))) void*)l, 16, 0, 0);
}

// ---------------------------------------------------------------------------
// Prep: fp32 x -> fp16 (RTN) combined [x1; x2], per-row El[r] =
// -gamma*log2e*|row|^2 (log2-domain), AND zero the 64 acc slots (block 0).
// ---------------------------------------------------------------------------
__global__ __launch_bounds__(256) void prep_kernel(
    const float* __restrict__ x1, const float* __restrict__ x2,
    _Float16* __restrict__ xh, float* __restrict__ El,
    double* __restrict__ acc, float gl, int N) {
    int tid = threadIdx.x;
    if (blockIdx.x == 0 && tid < 64) acc[tid] = 0.0;
    int r = blockIdx.x * 16 + (tid >> 4);
    if (r >= 2 * N) return;
    int l = tid & 15;
    const float* row = (r < N) ? x1 + (size_t)r * D : x2 + (size_t)(r - N) * D;
    float4 v0 = ((const float4*)row)[l * 2];
    float4 v1 = ((const float4*)row)[l * 2 + 1];
    float v[8] = {v0.x, v0.y, v0.z, v0.w, v1.x, v1.y, v1.z, v1.w};
    float p = 0.f;
    _Float16 h8[8];
#pragma unroll
    for (int j = 0; j < 8; ++j) {
        p = fmaf(v[j], v[j], p);
        h8[j] = (_Float16)v[j];   // RTN-even
    }
    *(uint4*)(xh + (size_t)r * D + l * 8) = *(uint4*)h8;
#pragma unroll
    for (int off = 8; off; off >>= 1) p += __shfl_down(p, off, 16);
    if (l == 0) El[r] = gl * p;   // gl = -gamma*log2e
}

// ---------------------------------------------------------------------------
// R16. Post-mortem chain:
//   R0/R12/R14: ~50-52us, MfmaUtil 26% -- pipe-time audit SUMS to measured
//     cycles (MFMA 40k + VALU 35k + trans 16k + LDS 25k ~= 120k cy). Pipes
//     serial. Occupancy axis falsified (R14: +50% waves, zero gain).
//   R15 (no LDS, B from L2, no barriers): 76.5us, MfmaUtil 17% -- L2
//     latency on the per-j critical path stalls everyone. LDS staging is
//     load-bearing. "Barriers are the serializer" falsified too.
// R16 = R14 base + IN-WAVE overlap (T15 double-pipeline):
//   * TWO C accumulators (CA/CB, static names per rule-20): MFMA of
//     half-tile ht fills one while the exp2/VALU epilogue of ht-1 drains
//     the other, interleaved per j-group (2 ds_read + 8 MFMA + 8 exp2 per
//     group -> matrix/trans/VALU pipes fed simultaneously from ONE wave).
//   * A-row loop split into two fixed-aBase sub-ranges (no control flow in
//     the steady loop); pipeline drains once per sub-range, restart wP=0.
//   * ea4 demoted to per-chunk L1-hit reloads (pays for CB's 32 regs;
//     peak ~160 of the 170 cap at (256,3); AGPR/VGPR unified file).
//   * j=0 MFMAs take a literal-zero C (free accumulator re-zero).
//   * zero-init C + wP=0 guard => first epilogue is finite*0 (no 0*Inf).
//   * sync skeleton EXACTLY R14's: top s_waitcnt vmcnt(4)+s_barrier, bottom
//     s_barrier+stage(ht+2). vmcnt(4) semantics: waits all but the 4 newest
//     (= bottom-stage of ht+1); mid-body El/A loads are older -> drained.
// Tripwires: WRITE_SIZE KB-scale (spill), bank conflict ~2.1M (accepted).
// If STILL ~50us: serial-sum model wrong -> R17 = template ablation.
// Signed weight: bi==bj: +1; same class off-diag: +2; cross class: -2.
// MFMA: v_mfma_f32_16x16x32_f16 (m89/m91-HW-verified C/D layout).
// ---------------------------------------------------------------------------
__global__ __launch_bounds__(256, 3) void mmd_mfma_kernel(
    const _Float16* __restrict__ xh, const float* __restrict__ El,
    double* __restrict__ acc, float c2l, int N) {
    __shared__ float4 smem[2][1024];  // 32 KiB: two 16 KiB B half-buffers

    int tid = threadIdx.x;
    int lane = tid & 63, wave = tid >> 6;      // 4 waves
    int quad = lane >> 4, l16 = lane & 15;
    int wrow = (wave & 1) * 64;                // 2 row-groups of 64
    int wcol = (wave >> 1) * 32;               // 2 col-groups of 32

    int nt2 = 2 * N / BM;        // 128 combined block-rows
    int half = N / BM;           // first `half` are x1
    int p = blockIdx.x / NSEG;   // strip pair: rows p and nt2-1-p
    int s = blockIdx.x % NSEG;
    int tpp = nt2 + 1;           // tiles per pair (129)
    int q = tpp / NSEG, r = tpp % NSEG;
    int t0 = s * q + (s < r ? s : r);
    int nt = q + (s < r ? 1 : 0);    // 10 or 11 tiles
    int H = 2 * nt;                  // half-tiles (BN=64 cols each)

    // staging geometry: 16 KiB / 256 thr / 16 B = 4 slots/thread.
    // row = slot>>4 (64 rows x 16 granules), granule XOR-swizzled by row&7.
    int goff[4];
#pragma unroll
    for (int i = 0; i < 4; ++i) {
        int slot = i * 256 + tid;
        int row = slot >> 4;
        int g = (slot & 15) ^ (row & 7);
        goff[i] = row * D + g * 8;
    }

    auto stage = [&](int b2Base, int buf) {
        const _Float16* src = xh + (size_t)b2Base * D;
#pragma unroll
        for (int i = 0; i < 4; ++i)
            async_cp16(src + goff[i], &smem[buf][i * 256 + tid]);
    };
    auto BI = [&](int tt) { return tt <= p ? p : nt2 - 1 - p; };
    auto BJ = [&](int tt) { return tt <= p ? tt : tt - p - 1; };

    // prologue: halves 0 and 1 of tile t0
    stage(BJ(t0) * BM, 0);
    stage(BJ(t0) * BM + BN, 1);

    f16x8 a[4][4];              // A fragments: 64 rows x K=128 (64 VGPR)
    f32x4 CA[4][2], CB[4][2];   // double accumulator (64, AGPR-eligible)
    const f32x4 CZ = {0.f, 0.f, 0.f, 0.f};
#pragma unroll
    for (int ti = 0; ti < 4; ++ti) {
        CA[ti][0] = CZ; CA[ti][1] = CZ;
        CB[ti][0] = CZ; CB[ti][1] = CZ;
    }

    float ebP0 = 0.f, ebP1 = 0.f, wP = 0.f;  // prev half-tile state
    int curABase = 0;
    double dsum = 0.0;
    f32x2 cc = {c2l, c2l};

    auto loadA = [&](int aBase) {
        curABase = aBase;
#pragma unroll
        for (int u = 0; u < 4; ++u) {
            int ar = aBase + wrow + u * 16 + l16;
#pragma unroll
            for (int j = 0; j < 4; ++j) {
                int g = (j >> 1) * 8 + (j & 1) * 4 + quad;
                a[u][j] = *(const f16x8*)(xh + (size_t)ar * D + g * 8);
            }
        }
    };

    // one epilogue chunk: prev-C rows ti=j (both tj halves). ea reloaded
    // per chunk (L1-hit, same 64 floats all sub-range; frees 16 regs).
    auto epiChunk = [&](const f32x4& d0, const f32x4& d1, int j,
                        f32x2& p20, f32x2& p21) {
        float4 ea = *(const float4*)&El[curABase + wrow + j * 16 + quad * 4];
        f32x2 eaxy = {ea.x, ea.y}, eazw = {ea.z, ea.w};
        f32x2 a01 = cc * f32x2{d0.x, d0.y} + eaxy;
        f32x2 a23 = cc * f32x2{d0.z, d0.w} + eazw;
        f32x2 b01 = cc * f32x2{d1.x, d1.y} + eaxy;
        f32x2 b23 = cc * f32x2{d1.z, d1.w} + eazw;
        f32x2 e0, e1, e2, e3;
        e0.x = __builtin_amdgcn_exp2f(a01.x); e0.y = __builtin_amdgcn_exp2f(a01.y);
        e1.x = __builtin_amdgcn_exp2f(a23.x); e1.y = __builtin_amdgcn_exp2f(a23.y);
        e2.x = __builtin_amdgcn_exp2f(b01.x); e2.y = __builtin_amdgcn_exp2f(b01.y);
        e3.x = __builtin_amdgcn_exp2f(b23.x); e3.y = __builtin_amdgcn_exp2f(b23.y);
        p20 += e0 + e1;
        p21 += e2 + e3;
    };
    auto epiFinish = [&](f32x2 p20, f32x2 p21) {
        float s0 = (p20.x + p20.y) * __builtin_amdgcn_exp2f(ebP0);
        float s1 = (p21.x + p21.y) * __builtin_amdgcn_exp2f(ebP1);
        dsum += (double)(s0 + s1) * (double)wP;
    };

    // one half-tile: MFMA into Cc, epilogue of PREV tile out of Cp,
    // interleaved per j-group so matrix/trans/VALU pipes co-issue.
    auto halfTile = [&](int ht, f32x4 (&Cc)[4][2], f32x4 (&Cp)[4][2]) {
        int tt = t0 + (ht >> 1), h = ht & 1;
        int bi = BI(tt), bj = BJ(tt);
        int bcolBase = bj * BM + h * BN;
        float w = (bi == bj) ? 1.0f : 2.0f;
        if ((bi < half) != (bj < half)) w = -2.0f;
        int cur = ht & 1;

        // counted wait: everything except the 4 newest (stage of ht+1)
        // drains -- incl. stage(ht), El loads, A loads. NEVER 0 mid-loop.
        if (ht + 1 < H) {
            asm volatile("s_waitcnt vmcnt(4)" ::: "memory");
        } else {
            asm volatile("s_waitcnt vmcnt(0)" ::: "memory");
        }
        __builtin_amdgcn_s_barrier();
        __builtin_amdgcn_sched_barrier(0);

        // B-side El for THIS half-tile (consumed next half-tile as "prev")
        int bcol0 = bcolBase + wcol + l16;
        float ebC0 = El[bcol0];
        float ebC1 = El[bcol0 + 16];

        f32x2 p20 = {0.f, 0.f}, p21 = {0.f, 0.f};

#pragma unroll
        for (int j = 0; j < 4; ++j) {
            int gb = (j >> 1) * 8 + (j & 1) * 4 + quad;
            int br0 = wcol + l16, br1 = wcol + 16 + l16;
            f16x8 b0 = *(const f16x8*)&smem[cur][br0 * 16 + (gb ^ (br0 & 7))];
            f16x8 b1 = *(const f16x8*)&smem[cur][br1 * 16 + (gb ^ (br1 & 7))];
            if (j == 0) {   // zero-C: re-zeroes the accumulator for free
#pragma unroll
                for (int ti = 0; ti < 4; ++ti) {
                    Cc[ti][0] = __builtin_amdgcn_mfma_f32_16x16x32_f16(
                        a[ti][0], b0, CZ, 0, 0, 0);
                    Cc[ti][1] = __builtin_amdgcn_mfma_f32_16x16x32_f16(
                        a[ti][0], b1, CZ, 0, 0, 0);
                }
            } else {
#pragma unroll
                for (int ti = 0; ti < 4; ++ti) {
                    Cc[ti][0] = __builtin_amdgcn_mfma_f32_16x16x32_f16(
                        a[ti][j], b0, Cc[ti][0], 0, 0, 0);
                    Cc[ti][1] = __builtin_amdgcn_mfma_f32_16x16x32_f16(
                        a[ti][j], b1, Cc[ti][1], 0, 0, 0);
                }
            }
            // prev-tile epilogue chunk (independent of the MFMAs above; the
            // scheduler co-issues trans/VALU with the matrix pipe)
            epiChunk(Cp[j][0], Cp[j][1], j, p20, p21);
        }
        epiFinish(p20, p21);

        // all waves done reading buf[cur] -> overwrite with half-tile ht+2
        __builtin_amdgcn_sched_barrier(0);
        __builtin_amdgcn_s_barrier();
        __builtin_amdgcn_sched_barrier(0);
        if (ht + 2 < H) {
            int tn = t0 + ((ht + 2) >> 1);     // (ht+2)&1 == h
            stage(BJ(tn) * BM + h * BN, cur);
        }
        wP = w; ebP0 = ebC0; ebP1 = ebC1;      // current becomes prev
    };

    auto drain = [&](f32x4 (&Cp)[4][2]) {      // exposed epilogue, 2x/block
        f32x2 p20 = {0.f, 0.f}, p21 = {0.f, 0.f};
#pragma unroll
        for (int j = 0; j < 4; ++j) epiChunk(Cp[j][0], Cp[j][1], j, p20, p21);
        epiFinish(p20, p21);
    };

    // split range at the strip-row change so aBase is loop-invariant
    int tiles1 = p + 1 - t0;
    if (tiles1 < 0) tiles1 = 0;
    if (tiles1 > nt) tiles1 = nt;
    int H1 = 2 * tiles1;

    if (H1 > 0) {
        loadA(p * BM);
        for (int k = 0; k < H1; k += 2) {
            halfTile(k, CA, CB);
            halfTile(k + 1, CB, CA);
        }
        drain(CB);
        wP = 0.f;                 // restart pipeline for sub-range 2
    }
    if (H1 < H) {
        loadA((nt2 - 1 - p) * BM);
        for (int k = H1; k < H; k += 2) {
            halfTile(k, CA, CB);
            halfTile(k + 1, CB, CA);
        }
        drain(CB);
    }

    // block reduction (once per block)
#pragma unroll
    for (int off = 32; off; off >>= 1) dsum += __shfl_down(dsum, off);
    double* red = (double*)&smem[0][0];
    if (lane == 0) red[wave] = dsum;
    __syncthreads();
    if (tid == 0)
        atomicAdd(&acc[blockIdx.x & 63], red[0] + red[1] + red[2] + red[3]);
}

// ---------------------------------------------------------------------------
// Finalize: out = sqrt(max(S/N^2, 0)), S already = S11 + S22 - 2*S12.
// ---------------------------------------------------------------------------
__global__ __launch_bounds__(64) void mmd_finalize_kernel(
    const double* __restrict__ acc, float* __restrict__ out, int N) {
    int l = threadIdx.x;
    double v = acc[l];
#pragma unroll
    for (int off = 32; off; off >>= 1) v += __shfl_down(v, off);
    if (l == 0) {
        double nn = (double)N * (double)N;
        double s = v / nn;
        out[0] = (float)sqrt(s > 0.0 ? s : 0.0);
    }
}

extern "C" void kernel_launch(void* const* d_in, const int* in_sizes, int n_in,
                              void* d_out, int out_size, void* d_ws, size_t ws_size,
                              hipStream_t stream) {
    const float* x1 = (const float*)d_in[0];
    const float* x2 = (const float*)d_in[1];
    int N = in_sizes[0] / D;  // 8192

    // ws layout: [0,512) acc (64 doubles); El @8192 (2N f32);
    // xh @73728 (2N*128 fp16 = 4 MB). Total ~4.07 MB.
    double* acc = (double*)d_ws;
    float* El = (float*)((char*)d_ws + 8192);
    _Float16* xh = (_Float16*)((char*)d_ws + 73728);

    double lg = lgamma(0.5 * (D + 1)) - lgamma(0.5 * D);
    double gz = 2.0 * exp(lg);
    double gamma = 1.0 / (2.0 * gz * gz);
    float gl = (float)(-gamma * LOG2E);        // El scale
    float c2l = (float)(2.0 * gamma * LOG2E);  // dot scale (log2 domain)

    prep_kernel<<<(2 * N + 15) / 16, 256, 0, stream>>>(x1, x2, xh, El, acc, gl, N);

    int nblocks = 64 * NSEG;   // 64 strip-pairs x 12 segments = 768 = 3/CU
    mmd_mfma_kernel<<<nblocks, 256, 0, stream>>>(xh, El, acc, c2l, N);

    mmd_finalize_kernel<<<1, 64, 0, stream>>>(acc, (float*)d_out, N);
}

// Round 7
// 131.842 us; speedup vs baseline: 1.7133x; 1.7133x over previous
//
#include <hip/hip_runtime.h>
#include <cmath>

#define D 128
#define BM 128   // strip tile is 128x128; wave owns 64 rows x 64 cols of it
#define NSEG 8   // segments per strip-pair -> 64*8 = 512 blocks = 2/CU exactly
#define LOG2E 1.4426950408889634

typedef __attribute__((ext_vector_type(8))) _Float16 f16x8;
typedef __attribute__((ext_vector_type(4))) float f32x4;
typedef __attribute__((ext_vector_type(2))) float f32x2;

// ---------------------------------------------------------------------------
// Prep: fp32 x -> fp16 (RTN) combined [x1; x2], per-row El[r] =
// -gamma*log2e*|row|^2 (log2-domain), AND zero the 64 acc slots (block 0).
// ---------------------------------------------------------------------------
__global__ __launch_bounds__(256) void prep_kernel(
    const float* __restrict__ x1, const float* __restrict__ x2,
    _Float16* __restrict__ xh, float* __restrict__ El,
    double* __restrict__ acc, float gl, int N) {
    int tid = threadIdx.x;
    if (blockIdx.x == 0 && tid < 64) acc[tid] = 0.0;
    int r = blockIdx.x * 16 + (tid >> 4);
    if (r >= 2 * N) return;
    int l = tid & 15;
    const float* row = (r < N) ? x1 + (size_t)r * D : x2 + (size_t)(r - N) * D;
    float4 v0 = ((const float4*)row)[l * 2];
    float4 v1 = ((const float4*)row)[l * 2 + 1];
    float v[8] = {v0.x, v0.y, v0.z, v0.w, v1.x, v1.y, v1.z, v1.w};
    float p = 0.f;
    _Float16 h8[8];
#pragma unroll
    for (int j = 0; j < 8; ++j) {
        p = fmaf(v[j], v[j], p);
        h8[j] = (_Float16)v[j];   // RTN-even
    }
    *(uint4*)(xh + (size_t)r * D + l * 8) = *(uint4*)h8;
#pragma unroll
    for (int off = 8; off; off >>= 1) p += __shfl_down(p, off, 16);
    if (l == 0) El[r] = gl * p;   // gl = -gamma*log2e
}

// ---------------------------------------------------------------------------
// R17. Post-mortem chain:
//   R0/R12/R14 ~50-52us @ MfmaUtil 26%: pipe-time audit SUMS to measured
//     cycles -- pipes serial + ~30% stall. Barrier phase-lock suspected.
//   R15 (B from L2 per-j, no LDS/barriers): 76us -- NOT because LDS is
//     magic, but because lookahead was ~150cy < L2 latency. Loads sat on
//     the MFMA critical path (MfmaUtil 17%).
//   R16 (double-C in-wave overlap): SPILLED (WRITE_SIZE 108MB) at the
//     (256,3)=170 cap. Theory untested; implementation too fat.
// R17 = wave-independent workers, barrier-free, register-staged B:
//   * Wave (r,c) owns rows 64r / cols 64c of each strip tile; iterates
//     32-col sub-tiles. A in regs (64). B sub-tile = B[2][4] f16x8 = 32
//     regs, DOUBLE-BUFFERED (Ba/Bb static names, 2x-unrolled loop).
//   * Loads for sub-tile k+1 issue BEFORE compute of sub-tile k -> ~1200cy
//     lookahead >> L2 latency. MFMA operands are all-register; NO loads on
//     the compute path. Compiler emits exact counted vmcnt (no inline asm).
//   * ZERO barriers, zero LDS tile (only a 4-double reduction scratch):
//     8 free-running waves/CU phase-skew -> MFMA of one wave overlaps
//     exp2/VALU of another (m114). This is what R12/R14's s_barriers
//     structurally prevented.
//   * Budget at (256,2)=256 cap: a 64 + Ba/Bb 64 + C 32 + ea4 16 + misc
//     ~30 = ~210. 40+ regs slack. 512 blocks = exactly 2/CU.
//   * Correctness: R15's proven global B-frag indexing + R14's proven
//     epilogue; only the schedule differs.
// Tripwire: WRITE_SIZE must stay KB-scale (R16's spill mode).
// Pre-registered fallback: ~50us again => serial-pipe model wrong =>
// R18 is a template ablation (MFMA-only / epilogue-only), not a schedule.
// Signed weight: bi==bj: +1; same class off-diag: +2; cross class: -2.
// MFMA: v_mfma_f32_16x16x32_f16 (m89/m91-HW-verified C/D layout).
// ---------------------------------------------------------------------------
__global__ __launch_bounds__(256, 2) void mmd_mfma_kernel(
    const _Float16* __restrict__ xh, const float* __restrict__ El,
    double* __restrict__ acc, float c2l, int N) {
    __shared__ double red[4];   // reduction scratch only

    int tid = threadIdx.x;
    int lane = tid & 63, wave = tid >> 6;      // 4 waves
    int quad = lane >> 4, l16 = lane & 15;
    int wrow = (wave & 1) * 64;                // A row group (64 rows)
    int wcolBase = (wave >> 1) * 64;           // B col group (2 sub-tiles)

    int nt2 = 2 * N / BM;        // 128 combined block-rows
    int half = N / BM;           // first `half` are x1
    int p = blockIdx.x / NSEG;   // strip pair: rows p and nt2-1-p
    int s = blockIdx.x % NSEG;
    int tpp = nt2 + 1;           // tiles per pair (129)
    int q = tpp / NSEG, r = tpp % NSEG;
    int t0 = s * q + (s < r ? s : r);
    int nt = q + (s < r ? 1 : 0);    // 16 or 17 tiles
    int S = 2 * nt;                  // 32-col sub-tiles for this wave (even)

    auto BI = [&](int tt) { return tt <= p ? p : nt2 - 1 - p; };
    auto BJ = [&](int tt) { return tt <= p ? tt : tt - p - 1; };
    // sub-tile k -> this wave's global column base
    auto subCol = [&](int k) {
        int tt = t0 + (k >> 1);
        return BJ(tt) * BM + wcolBase + (k & 1) * 32;
    };

    f16x8 a[4][4];       // A fragments: 64 rows x K=128 (64 VGPR)
    float4 ea4[4];       // A-side El
    int curA = -1;
    double dsum = 0.0;
    f32x2 cc = {c2l, c2l};

    // load one 32-col B sub-tile into 8 f16x8 frags (static indices).
    // R15-proven indexing: row br = cb + u*16 + l16, k-granule per (j,quad).
    auto loadB = [&](f16x8 (&B)[2][4], int cb) {
#pragma unroll
        for (int u = 0; u < 2; ++u) {
#pragma unroll
            for (int j = 0; j < 4; ++j) {
                int g = (j >> 1) * 8 + (j & 1) * 4 + quad;
                int br = cb + u * 16 + l16;
                B[u][j] = *(const f16x8*)(xh + (size_t)br * D + g * 8);
            }
        }
    };

    // compute + fused epilogue for one sub-tile (C is scoped => 32 regs
    // live only here; zero-C j=0 MFMA re-zeroes the accumulator for free).
    auto computeEpi = [&](const f16x8 (&B)[2][4], int k) {
        int tt = t0 + (k >> 1);
        int bi = BI(tt), bj = BJ(tt);
        int aBase = bi * BM;
        if (aBase != curA) {   // strip-row change: <= 2x per block
            curA = aBase;
#pragma unroll
            for (int u = 0; u < 4; ++u) {
                int ar = aBase + wrow + u * 16 + l16;
#pragma unroll
                for (int j = 0; j < 4; ++j) {
                    int g = (j >> 1) * 8 + (j & 1) * 4 + quad;
                    a[u][j] = *(const f16x8*)(xh + (size_t)ar * D + g * 8);
                }
            }
            int arow0 = aBase + wrow + quad * 4;
#pragma unroll
            for (int ti = 0; ti < 4; ++ti)
                ea4[ti] = *(const float4*)&El[arow0 + ti * 16];
        }
        float w = (bi == bj) ? 1.0f : 2.0f;
        if ((bi < half) != (bj < half)) w = -2.0f;
        int cb = bj * BM + wcolBase + (k & 1) * 32;
        int bcol0 = cb + l16;
        float eb0 = El[bcol0];
        float eb1 = El[bcol0 + 16];

        const f32x4 CZ = {0.f, 0.f, 0.f, 0.f};
        f32x4 C[4][2];
#pragma unroll
        for (int ti = 0; ti < 4; ++ti) {
            C[ti][0] = __builtin_amdgcn_mfma_f32_16x16x32_f16(
                a[ti][0], B[0][0], CZ, 0, 0, 0);
            C[ti][1] = __builtin_amdgcn_mfma_f32_16x16x32_f16(
                a[ti][0], B[1][0], CZ, 0, 0, 0);
        }
#pragma unroll
        for (int j = 1; j < 4; ++j)
#pragma unroll
            for (int ti = 0; ti < 4; ++ti) {
                C[ti][0] = __builtin_amdgcn_mfma_f32_16x16x32_f16(
                    a[ti][j], B[0][j], C[ti][0], 0, 0, 0);
                C[ti][1] = __builtin_amdgcn_mfma_f32_16x16x32_f16(
                    a[ti][j], B[1][j], C[ti][1], 0, 0, 0);
            }

        // epilogue: entry = exp2(c2l*d + ea) * 2^eb (m89-verified layout:
        // col = lane&15, row = quad*4 + reg)
        float lsum = 0.f;
#pragma unroll
        for (int tj = 0; tj < 2; ++tj) {
            f32x2 p2 = {0.f, 0.f};
#pragma unroll
            for (int ti = 0; ti < 4; ++ti) {
                f32x4 d = C[ti][tj];
                f32x2 a01 = cc * f32x2{d.x, d.y} + f32x2{ea4[ti].x, ea4[ti].y};
                f32x2 a23 = cc * f32x2{d.z, d.w} + f32x2{ea4[ti].z, ea4[ti].w};
                f32x2 e, e2;
                e.x = __builtin_amdgcn_exp2f(a01.x);
                e.y = __builtin_amdgcn_exp2f(a01.y);
                e2.x = __builtin_amdgcn_exp2f(a23.x);
                e2.y = __builtin_amdgcn_exp2f(a23.y);
                p2 += e + e2;
            }
            lsum = fmaf(p2.x + p2.y,
                        __builtin_amdgcn_exp2f(tj ? eb1 : eb0), lsum);
        }
        dsum += (double)lsum * (double)w;
    };

    // software pipeline: Ba/Bb ping-pong, loads one full sub-tile ahead.
    f16x8 Ba[2][4], Bb[2][4];
    loadB(Ba, subCol(0));
    for (int k = 0; k < S; k += 2) {
        loadB(Bb, subCol(k + 1));              // k+1 < S always (S even)
        computeEpi(Ba, k);
        loadB(Ba, subCol(k + 2 < S ? k + 2 : 0));  // tail: dummy reload
        computeEpi(Bb, k + 1);
    }

    // block reduction (the ONLY synchronization in the kernel)
#pragma unroll
    for (int off = 32; off; off >>= 1) dsum += __shfl_down(dsum, off);
    if (lane == 0) red[wave] = dsum;
    __syncthreads();
    if (tid == 0)
        atomicAdd(&acc[blockIdx.x & 63], red[0] + red[1] + red[2] + red[3]);
}

// ---------------------------------------------------------------------------
// Finalize: out = sqrt(max(S/N^2, 0)), S already = S11 + S22 - 2*S12.
// ---------------------------------------------------------------------------
__global__ __launch_bounds__(64) void mmd_finalize_kernel(
    const double* __restrict__ acc, float* __restrict__ out, int N) {
    int l = threadIdx.x;
    double v = acc[l];
#pragma unroll
    for (int off = 32; off; off >>= 1) v += __shfl_down(v, off);
    if (l == 0) {
        double nn = (double)N * (double)N;
        double s = v / nn;
        out[0] = (float)sqrt(s > 0.0 ? s : 0.0);
    }
}

extern "C" void kernel_launch(void* const* d_in, const int* in_sizes, int n_in,
                              void* d_out, int out_size, void* d_ws, size_t ws_size,
                              hipStream_t stream) {
    const float* x1 = (const float*)d_in[0];
    const float* x2 = (const float*)d_in[1];
    int N = in_sizes[0] / D;  // 8192

    // ws layout: [0,512) acc (64 doubles); El @8192 (2N f32);
    // xh @73728 (2N*128 fp16 = 4 MB). Total ~4.07 MB.
    double* acc = (double*)d_ws;
    float* El = (float*)((char*)d_ws + 8192);
    _Float16* xh = (_Float16*)((char*)d_ws + 73728);

    double lg = lgamma(0.5 * (D + 1)) - lgamma(0.5 * D);
    double gz = 2.0 * exp(lg);
    double gamma = 1.0 / (2.0 * gz * gz);
    float gl = (float)(-gamma * LOG2E);        // El scale
    float c2l = (float)(2.0 * gamma * LOG2E);  // dot scale (log2 domain)

    prep_kernel<<<(2 * N + 15) / 16, 256, 0, stream>>>(x1, x2, xh, El, acc, gl, N);

    int nblocks = 64 * NSEG;   // 64 strip-pairs x 8 segments = 512 = 2/CU
    mmd_mfma_kernel<<<nblocks, 256, 0, stream>>>(xh, El, acc, c2l, N);

    mmd_finalize_kernel<<<1, 64, 0, stream>>>(acc, (float*)d_out, N);
}